// Round 14
// baseline (155.717 us; speedup 1.0000x reference)
//
#include <hip/hip_runtime.h>

#define HH 1024
#define WW 1024
#define NB 8
constexpr int PLANE = HH * WW;

#define S   84   // LDS plane stride (u32 units), mult of 4
#define RG  46   // staged region rows
#define NTHR 512

typedef _Float16 h2 __attribute__((ext_vector_type(2)));

__device__ __forceinline__ int clampi(int v, int lo, int hi) {
    return v < lo ? lo : (v > hi ? hi : v);
}

union U2H { unsigned u; h2 h; };
__device__ __forceinline__ h2 u2h(unsigned v) { U2H x; x.u = v; return x.h; }
__device__ __forceinline__ unsigned h2u(h2 h) { U2H x; x.h = h; return x.u; }
__device__ __forceinline__ unsigned packdiff(float a, float b) {
    h2 h; h.x = (_Float16)a; h.y = (_Float16)b; return h2u(h);
}
__device__ __forceinline__ h2 swap16(h2 x) {
    unsigned u = h2u(x);
    return u2h(__builtin_amdgcn_alignbit(u, u, 16));
}

__device__ __forceinline__ void cswap2(h2& a, h2& b) {
    h2 lo = __builtin_elementwise_min(a, b);
    b = __builtin_elementwise_max(a, b);
    a = lo;
}

// rank 4 (0-indexed) of 8, both fp16 lanes. Pruned Batcher network (validated r1-r13).
__device__ __forceinline__ h2 med8p(h2 v0, h2 v1, h2 v2, h2 v3,
                                    h2 v4, h2 v5, h2 v6, h2 v7) {
    cswap2(v0, v1); cswap2(v2, v3); cswap2(v4, v5); cswap2(v6, v7);
    cswap2(v0, v2); cswap2(v1, v3); cswap2(v4, v6); cswap2(v5, v7);
    cswap2(v1, v2); cswap2(v5, v6);
    h2 p2 = __builtin_elementwise_min(v2, v6), p3 = __builtin_elementwise_min(v3, v7);
    h2 p4 = __builtin_elementwise_max(v0, v4), p5 = __builtin_elementwise_max(v1, v5);
    return __builtin_elementwise_max(__builtin_elementwise_min(p3, p5),
                                     __builtin_elementwise_max(p2, p4));
}

// rank 2 (0-indexed) of 4, both lanes.
__device__ __forceinline__ h2 med4p(h2 a, h2 b, h2 c, h2 d) {
    h2 ab_hi = __builtin_elementwise_max(a, b), ab_lo = __builtin_elementwise_min(a, b);
    h2 cd_hi = __builtin_elementwise_max(c, d), cd_lo = __builtin_elementwise_min(c, d);
    return __builtin_elementwise_max(__builtin_elementwise_min(ab_hi, cd_hi),
                                     __builtin_elementwise_max(ab_lo, cd_lo));
}

__device__ __forceinline__ void demo_acc(float v, int pyn, int pxn, int ady, int adx,
                                         float& accR, float& accG, float& accB) {
    bool isr = (pyn == 0) && (pxn == 1);
    bool isb = (pyn == 1) && (pxn == 0);
    float wrb = 0.25f * (float)((2 - ady) * (2 - adx));
    int man = ady + adx;
    float wg = (man == 0) ? 1.0f : ((man == 1) ? 0.25f : 0.0f);
    accR += isr ? wrb * v : 0.0f;
    accB += isb ? wrb * v : 0.0f;
    accG += (!isr && !isb) ? wg * v : 0.0f;
}

// shared quad demosaick math: w[i][j] = raw value at (rA-1+i, colbase+1+j); writes 2 quads
__device__ __forceinline__ void demo_quads2(const float w[4][6], unsigned* __restrict__ sdRB,
                                            _Float16* __restrict__ sG, int a0base) {
#pragma unroll
    for (int q = 0; q < 2; ++q) {
        int jb = 1 + 2 * q;
        float g00 = w[1][jb];
        float r00 = 0.5f * (w[1][jb - 1] + w[1][jb + 1]);
        float b00 = 0.5f * (w[0][jb] + w[2][jb]);
        float r01 = w[1][jb + 1];
        float g01 = 0.25f * (w[0][jb + 1] + w[2][jb + 1] + w[1][jb] + w[1][jb + 2]);
        float b01 = 0.25f * (w[0][jb] + w[0][jb + 2] + w[2][jb] + w[2][jb + 2]);
        float b10 = w[2][jb];
        float g10 = 0.25f * (w[1][jb] + w[3][jb] + w[2][jb - 1] + w[2][jb + 1]);
        float r10 = 0.25f * (w[1][jb - 1] + w[1][jb + 1] + w[3][jb - 1] + w[3][jb + 1]);
        float g11 = w[2][jb + 1];
        float r11 = 0.5f * (w[1][jb + 1] + w[3][jb + 1]);
        float b11 = 0.5f * (w[2][jb] + w[2][jb + 2]);
        int a0 = a0base + 2 * q;
        h2 gh0; gh0.x = (_Float16)g00; gh0.y = (_Float16)g01;
        h2 gh1; gh1.x = (_Float16)g10; gh1.y = (_Float16)g11;
        *reinterpret_cast<h2*>(&sG[a0]) = gh0;
        *reinterpret_cast<h2*>(&sG[a0 + S]) = gh1;
        *reinterpret_cast<uint2*>(&sdRB[a0]) =
            make_uint2(packdiff(r00 - g00, b00 - g00), packdiff(r01 - g01, b01 - g01));
        *reinterpret_cast<uint2*>(&sdRB[a0 + S]) =
            make_uint2(packdiff(r10 - g10, b10 - g10), packdiff(r11 - g11, b11 - g11));
    }
}

// ---------- vector LDS access helpers (CA = c0 & 3, 0 or 2) ----------
template <int CA>
__device__ __forceinline__ void load4u(const unsigned* row, int c0, unsigned w[4]) {
    if constexpr (CA == 0) {
        uint4 q = *reinterpret_cast<const uint4*>(row + c0);
        w[0] = q.x; w[1] = q.y; w[2] = q.z; w[3] = q.w;
    } else {
        uint2 a = *reinterpret_cast<const uint2*>(row + c0);
        uint2 b = *reinterpret_cast<const uint2*>(row + c0 + 2);
        w[0] = a.x; w[1] = a.y; w[2] = b.x; w[3] = b.y;
    }
}
template <int CA>
__device__ __forceinline__ void load6u(const unsigned* row, int c0, unsigned w[6]) {
    if constexpr (CA == 0) {
        uint4 q = *reinterpret_cast<const uint4*>(row + c0);
        w[0] = row[c0 - 1];
        w[1] = q.x; w[2] = q.y; w[3] = q.z; w[4] = q.w;
        w[5] = row[c0 + 4];
    } else {
        uint4 a = *reinterpret_cast<const uint4*>(row + c0 - 2);
        uint4 b = *reinterpret_cast<const uint4*>(row + c0 + 2);
        w[0] = a.y; w[1] = a.z; w[2] = a.w; w[3] = b.x; w[4] = b.y; w[5] = b.z;
    }
}
template <int CA>
__device__ __forceinline__ void store4u(unsigned* row, int c0, const unsigned v[4]) {
    if constexpr (CA == 0) {
        *reinterpret_cast<uint4*>(row + c0) = make_uint4(v[0], v[1], v[2], v[3]);
    } else {
        *reinterpret_cast<uint2*>(row + c0) = make_uint2(v[0], v[1]);
        *reinterpret_cast<uint2*>(row + c0 + 2) = make_uint2(v[2], v[3]);
    }
}

// ---------- phase 1: u = -med8(diffs), 2 rows x 4 cols per thread ----------
template <int R0, int NRP, int C0, int NG>
__device__ __forceinline__ void p1_int(const unsigned* __restrict__ sdRB,
                                       unsigned* __restrict__ uRB, int tid) {
    static_assert((C0 & 3) == 2, "p1_int needs C0 % 4 == 2");
    if (tid < NRP * NG) {
        int rp = tid / NG, g = tid - rp * NG;
        int r0 = R0 + 2 * rp;
        int c0 = C0 + 4 * g;
        int B = c0 - 2;
        unsigned w[4][6];
#pragma unroll
        for (int i = 0; i < 4; ++i) {
            const unsigned* row = &sdRB[(r0 - 1 + i) * S + B];
            uint4 q0 = *reinterpret_cast<const uint4*>(row);
            uint4 q1 = *reinterpret_cast<const uint4*>(row + 4);
            w[i][0] = q0.y; w[i][1] = q0.z; w[i][2] = q0.w;
            w[i][3] = q1.x; w[i][4] = q1.y; w[i][5] = q1.z;
        }
#pragma unroll
        for (int rr = 0; rr < 2; ++rr) {
            unsigned rv[4];
#pragma unroll
            for (int i = 0; i < 4; ++i) {
                h2 m = med8p(u2h(w[rr][i]), u2h(w[rr][i + 1]), u2h(w[rr][i + 2]),
                             u2h(w[rr + 1][i]), u2h(w[rr + 1][i + 2]),
                             u2h(w[rr + 2][i]), u2h(w[rr + 2][i + 1]), u2h(w[rr + 2][i + 2]));
                rv[i] = h2u(-m);
            }
            store4u<2>(&uRB[(r0 + rr) * S], c0, rv);
        }
    }
}

// ---------- phase 2 (packed fp16): Rn,Bn,Gn on 2x4 px per thread ----------
template <int R0, int NRP, int C0, int NG, int CA, bool FINAL>
__device__ __forceinline__ void p2_int(_Float16* __restrict__ sG, unsigned* __restrict__ sdRB,
                                       const unsigned* __restrict__ uRB, int tid,
                                       int y0, int x0,
                                       float* __restrict__ oR, float* __restrict__ oG,
                                       float* __restrict__ oB) {
    if (tid < NRP * NG) {
        int rp = tid / NG, g = tid - rp * NG;
        int r0 = R0 + 2 * rp;
        int c0 = C0 + 4 * g;
        unsigned wm[4], wp[4], w0[6], w1[6];
        load4u<CA>(&uRB[(r0 - 1) * S], c0, wm);
        load6u<CA>(&uRB[(r0) * S], c0, w0);
        load6u<CA>(&uRB[(r0 + 1) * S], c0, w1);
        load4u<CA>(&uRB[(r0 + 2) * S], c0, wp);
        h2 ga0 = *reinterpret_cast<const h2*>(&sG[r0 * S + c0]);
        h2 ga1 = *reinterpret_cast<const h2*>(&sG[r0 * S + c0 + 2]);
        h2 gb0 = *reinterpret_cast<const h2*>(&sG[(r0 + 1) * S + c0]);
        h2 gb1 = *reinterpret_cast<const h2*>(&sG[(r0 + 1) * S + c0 + 2]);
        _Float16 gr0[4] = {ga0.x, ga0.y, ga1.x, ga1.y};
        _Float16 gr1[4] = {gb0.x, gb0.y, gb1.x, gb1.y};
        const h2 half2v = {(_Float16)0.5f, (_Float16)0.5f};

        unsigned nd0[4], nd1[4];
        float R4[2][4], G4[2][4], B4[2][4];
#pragma unroll
        for (int i = 0; i < 4; ++i) {
            {
                h2 m = med4p(u2h(wm[i]), u2h(w0[i]), u2h(w0[i + 2]), u2h(w1[i + 1]));
                h2 uc = u2h(w0[i + 1]);
                h2 gg; gg.x = gr0[i]; gg.y = gr0[i];
                h2 RB = gg - uc;
                h2 Gn2 = ((m + swap16(m)) + (RB + swap16(RB))) * half2v;
                if constexpr (FINAL) {
                    R4[0][i] = (float)RB.x; B4[0][i] = (float)RB.y; G4[0][i] = (float)Gn2.x;
                } else {
                    nd0[i] = h2u(RB - Gn2);
                    gr0[i] = Gn2.x;
                }
            }
            {
                h2 m = med4p(u2h(w0[i + 1]), u2h(w1[i]), u2h(w1[i + 2]), u2h(wp[i]));
                h2 uc = u2h(w1[i + 1]);
                h2 gg; gg.x = gr1[i]; gg.y = gr1[i];
                h2 RB = gg - uc;
                h2 Gn2 = ((m + swap16(m)) + (RB + swap16(RB))) * half2v;
                if constexpr (FINAL) {
                    R4[1][i] = (float)RB.x; B4[1][i] = (float)RB.y; G4[1][i] = (float)Gn2.x;
                } else {
                    nd1[i] = h2u(RB - Gn2);
                    gr1[i] = Gn2.x;
                }
            }
        }
        if constexpr (FINAL) {
#pragma unroll
            for (int rr = 0; rr < 2; ++rr) {
                size_t o = (size_t)(y0 + r0 + rr) * WW + (x0 + c0);
                *reinterpret_cast<float4*>(&oR[o]) = make_float4(R4[rr][0], R4[rr][1], R4[rr][2], R4[rr][3]);
                *reinterpret_cast<float4*>(&oG[o]) = make_float4(G4[rr][0], G4[rr][1], G4[rr][2], G4[rr][3]);
                *reinterpret_cast<float4*>(&oB[o]) = make_float4(B4[rr][0], B4[rr][1], B4[rr][2], B4[rr][3]);
            }
        } else {
            h2 s00; s00.x = gr0[0]; s00.y = gr0[1];
            h2 s01; s01.x = gr0[2]; s01.y = gr0[3];
            h2 s10; s10.x = gr1[0]; s10.y = gr1[1];
            h2 s11; s11.x = gr1[2]; s11.y = gr1[3];
            *reinterpret_cast<h2*>(&sG[r0 * S + c0]) = s00;
            *reinterpret_cast<h2*>(&sG[r0 * S + c0 + 2]) = s01;
            *reinterpret_cast<h2*>(&sG[(r0 + 1) * S + c0]) = s10;
            *reinterpret_cast<h2*>(&sG[(r0 + 1) * S + c0 + 2]) = s11;
            store4u<CA>(&sdRB[r0 * S], c0, nd0);
            store4u<CA>(&sdRB[(r0 + 1) * S], c0, nd1);
        }
    }
}

// ---------- halo refresh: copy clamped-source values into out-of-image cells ----------
__device__ __forceinline__ void refresh_d(unsigned* __restrict__ sdRB, _Float16* __restrict__ sG,
                                          int tid, int y0, int x0,
                                          int rlo, int nr, int clo, int nc) {
    for (int t = tid; t < nr * nc; t += NTHR) {
        int r = rlo + t / nc, c = clo + t - (t / nc) * nc;
        int gy = y0 + r, gx = x0 + c;
        if ((unsigned)gy < (unsigned)HH && (unsigned)gx < (unsigned)WW) continue;
        int rs = clampi(gy, 0, HH - 1) - y0, cs = clampi(gx, 0, WW - 1) - x0;
        sdRB[r * S + c] = sdRB[rs * S + cs];
        sG[r * S + c] = sG[rs * S + cs];
    }
}
__device__ __forceinline__ void refresh_u(unsigned* __restrict__ uRB,
                                          int tid, int y0, int x0,
                                          int rlo, int nr, int clo, int nc) {
    for (int t = tid; t < nr * nc; t += NTHR) {
        int r = rlo + t / nc, c = clo + t - (t / nc) * nc;
        int gy = y0 + r, gx = x0 + c;
        if ((unsigned)gy < (unsigned)HH && (unsigned)gx < (unsigned)WW) continue;
        int rs = clampi(gy, 0, HH - 1) - y0, cs = clampi(gx, 0, WW - 1) - x0;
        uRB[r * S + c] = uRB[rs * S + cs];
    }
}

// ---------- the fused kernel: 64x32 output tile, 512 threads ----------
__global__ __launch_bounds__(512, 8) void fused_kernel(const float* __restrict__ img,
                                                       float* __restrict__ dst) {
    __shared__ __align__(16) unsigned smem[9660];
    unsigned* uRB = smem;
    unsigned* sdRB = smem + RG * S;
    _Float16* sG = reinterpret_cast<_Float16*>(smem + 2 * RG * S);
    float* sI = reinterpret_cast<float*>(smem);   // edge blocks: raw staged in uRB plane

    int bx = blockIdx.x, by = blockIdx.y, bb = blockIdx.z;
    int x0 = bx * 64 - 8, y0 = by * 32 - 7;
    const float* im = img + (size_t)bb * PLANE;
    float* oR = dst + (size_t)bb * 3 * PLANE;
    float* oG = oR + PLANE;
    float* oB = oR + 2 * PLANE;
    int tid = threadIdx.x;
    bool interior = (bx >= 1 && bx <= 14 && by >= 1 && by <= 30);

    if (interior) {
        // ---- demosaick straight from global (r13 path, proven) ----
        if (tid < 22 * 19) {
            int qi = tid / 19, g = tid - (tid / 19) * 19;
            int rA = 1 + 2 * qi;
            int B = 4 * g;
            const float* base = im + (size_t)(y0 + rA - 1) * WW + (x0 + B);
            float w[4][6];
#pragma unroll
            for (int i = 0; i < 4; ++i) {
                float4 a = *reinterpret_cast<const float4*>(base + (size_t)i * WW);
                float4 b = *reinterpret_cast<const float4*>(base + (size_t)i * WW + 4);
                w[i][0] = a.y; w[i][1] = a.z; w[i][2] = a.w;
                w[i][3] = b.x; w[i][4] = b.y; w[i][5] = b.z;
            }
            demo_quads2(w, sdRB, sG, rA * S + 2 + 4 * g);
        }
        __syncthreads();
        p1_int<2, 21, 2, 19>(sdRB, uRB, tid);
        __syncthreads();
        p2_int<3, 20, 4, 18, 0, false>(sG, sdRB, uRB, tid, y0, x0, oR, oG, oB);
        __syncthreads();
        p1_int<4, 19, 2, 19>(sdRB, uRB, tid);
        __syncthreads();
        p2_int<5, 18, 6, 17, 2, false>(sG, sdRB, uRB, tid, y0, x0, oR, oG, oB);
        __syncthreads();
        p1_int<6, 17, 6, 17>(sdRB, uRB, tid);
        __syncthreads();
        p2_int<7, 16, 8, 16, 0, true>(sG, sdRB, uRB, tid, y0, x0, oR, oG, oB);
    } else {
        // ---- edge block: stage clamped raw, vector phases + halo refreshes ----
        // in-image bounds within the region
        int rImgLo = (0 - y0) > 0 ? (0 - y0) : 0;
        int rImgHi = (1023 - y0) < (RG - 1) ? (1023 - y0) : (RG - 1);
        int cImgLo = (0 - x0) > 0 ? (0 - x0) : 0;
        int cImgHi = (1023 - x0) < 79 ? (1023 - x0) : 79;
        // vector-demosaick eligibility (quad window fully in-image)
        int raLo = rImgLo + 1; raLo += ((raLo & 1) ^ 1);          // odd, >= rImgLo+1
        int raHi = rImgHi - 2; raHi -= ((raHi & 1) ^ 1);          // odd
        if (raHi > 43) raHi = 43;
        int gLo = (cImgLo + 3) >> 2;
        int gHi = (cImgHi - 7) >> 2; if (gHi > 18) gHi = 18;
        int vcLo = 2 + 4 * gLo, vcHi = 5 + 4 * gHi;
        int nQr = (raHi - raLo) / 2 + 1;
        int nG = gHi - gLo + 1;

        // stage clamped raw
        for (int t = tid; t < RG * S; t += NTHR) {
            int r = t / S, c = t - (t / S) * S;
            int gy = clampi(y0 + r, 0, HH - 1), gx = clampi(x0 + c, 0, WW - 1);
            sI[r * S + c] = im[(size_t)gy * WW + gx];
        }
        __syncthreads();
        // vector demosaick on eligible quads (reads sI)
        if (tid < nQr * nG) {
            int qi = tid / nG, g = gLo + (tid - (tid / nG) * nG);
            int rA = raLo + 2 * qi;
            int B = 4 * g;
            float w[4][6];
#pragma unroll
            for (int i = 0; i < 4; ++i) {
                const float* row = &sI[(rA - 1 + i) * S + B];
                float4 a = *reinterpret_cast<const float4*>(row);
                float4 b = *reinterpret_cast<const float4*>(row + 4);
                w[i][0] = a.y; w[i][1] = a.z; w[i][2] = a.w;
                w[i][3] = b.x; w[i][4] = b.y; w[i][5] = b.z;
            }
            demo_quads2(w, sdRB, sG, rA * S + 2 + 4 * g);
        }
        // scalar demosaick for in-image cells not covered by the vector rect
        for (int t = tid; t < 44 * 76; t += NTHR) {
            int r = 1 + t / 76, c = 2 + t - (t / 76) * 76;
            if (r < rImgLo || r > rImgHi || c < cImgLo || c > cImgHi) continue;
            if (r >= raLo && r <= raHi + 1 && c >= vcLo && c <= vcHi) continue;
            int gy = y0 + r, gx = x0 + c;
            float accR = 0.f, accG = 0.f, accB = 0.f;
#pragma unroll
            for (int dy = -1; dy <= 1; ++dy)
#pragma unroll
                for (int dx = -1; dx <= 1; ++dx) {
                    int cy = clampi(gy + dy, 0, HH - 1);
                    int cx = clampi(gx + dx, 0, WW - 1);
                    float v = sI[(cy - y0) * S + (cx - x0)];
                    demo_acc(v, cy & 1, cx & 1, dy < 0 ? -dy : dy, dx < 0 ? -dx : dx,
                             accR, accG, accB);
                }
            sG[r * S + c] = (_Float16)accG;
            sdRB[r * S + c] = packdiff(accR - accG, accB - accG);
        }
        __syncthreads();
        refresh_d(sdRB, sG, tid, y0, x0, 1, 44, 2, 76);   // rows 1..44, cols 2..77
        __syncthreads();
        // iteration 1
        p1_int<2, 21, 2, 19>(sdRB, uRB, tid);             // (overwrites sI; sI is dead)
        __syncthreads();
        refresh_u(uRB, tid, y0, x0, 2, 42, 2, 76);        // rows 2..43, cols 2..77
        __syncthreads();
        p2_int<3, 20, 4, 18, 0, false>(sG, sdRB, uRB, tid, y0, x0, oR, oG, oB);
        __syncthreads();
        refresh_d(sdRB, sG, tid, y0, x0, 3, 40, 4, 72);   // rows 3..42, cols 4..75
        __syncthreads();
        // iteration 2
        p1_int<4, 19, 2, 19>(sdRB, uRB, tid);
        __syncthreads();
        refresh_u(uRB, tid, y0, x0, 4, 38, 2, 76);        // rows 4..41, cols 2..77
        __syncthreads();
        p2_int<5, 18, 6, 17, 2, false>(sG, sdRB, uRB, tid, y0, x0, oR, oG, oB);
        __syncthreads();
        refresh_d(sdRB, sG, tid, y0, x0, 5, 36, 6, 68);   // rows 5..40, cols 6..73
        __syncthreads();
        // iteration 3
        p1_int<6, 17, 6, 17>(sdRB, uRB, tid);
        __syncthreads();
        refresh_u(uRB, tid, y0, x0, 6, 34, 6, 68);        // rows 6..39, cols 6..73
        __syncthreads();
        p2_int<7, 16, 8, 16, 0, true>(sG, sdRB, uRB, tid, y0, x0, oR, oG, oB);
    }
}

extern "C" void kernel_launch(void* const* d_in, const int* in_sizes, int n_in,
                              void* d_out, int out_size, void* d_ws, size_t ws_size,
                              hipStream_t stream) {
    const float* img = (const float*)d_in[0];
    float* out = (float*)d_out;
    dim3 block(NTHR);
    dim3 grid(16, 32, NB);
    fused_kernel<<<grid, block, 0, stream>>>(img, out);
}

// Round 15
// 137.119 us; speedup vs baseline: 1.1356x; 1.1356x over previous
//
#include <hip/hip_runtime.h>

#define HH 1024
#define WW 1024
#define NB 8
constexpr int PLANE = HH * WW;

#define S   84   // LDS plane stride (u32 units), mult of 4
#define RG  46   // staged region rows
#define NTHR 512

typedef _Float16 h2 __attribute__((ext_vector_type(2)));

__device__ __forceinline__ int clampi(int v, int lo, int hi) {
    return v < lo ? lo : (v > hi ? hi : v);
}

union U2H { unsigned u; h2 h; };
__device__ __forceinline__ h2 u2h(unsigned v) { U2H x; x.u = v; return x.h; }
__device__ __forceinline__ unsigned h2u(h2 h) { U2H x; x.h = h; return x.u; }
__device__ __forceinline__ unsigned packdiff(float a, float b) {
    h2 h; h.x = (_Float16)a; h.y = (_Float16)b; return h2u(h);
}
__device__ __forceinline__ h2 swap16(h2 x) {
    unsigned u = h2u(x);
    return u2h(__builtin_amdgcn_alignbit(u, u, 16));
}

__device__ __forceinline__ void cswap2(h2& a, h2& b) {
    h2 lo = __builtin_elementwise_min(a, b);
    b = __builtin_elementwise_max(a, b);
    a = lo;
}

// rank 4 (0-indexed) of 8, both fp16 lanes. Pruned Batcher network (validated r1-r13).
__device__ __forceinline__ h2 med8p(h2 v0, h2 v1, h2 v2, h2 v3,
                                    h2 v4, h2 v5, h2 v6, h2 v7) {
    cswap2(v0, v1); cswap2(v2, v3); cswap2(v4, v5); cswap2(v6, v7);
    cswap2(v0, v2); cswap2(v1, v3); cswap2(v4, v6); cswap2(v5, v7);
    cswap2(v1, v2); cswap2(v5, v6);
    h2 p2 = __builtin_elementwise_min(v2, v6), p3 = __builtin_elementwise_min(v3, v7);
    h2 p4 = __builtin_elementwise_max(v0, v4), p5 = __builtin_elementwise_max(v1, v5);
    return __builtin_elementwise_max(__builtin_elementwise_min(p3, p5),
                                     __builtin_elementwise_max(p2, p4));
}

// rank 2 (0-indexed) of 4, both lanes.
__device__ __forceinline__ h2 med4p(h2 a, h2 b, h2 c, h2 d) {
    h2 ab_hi = __builtin_elementwise_max(a, b), ab_lo = __builtin_elementwise_min(a, b);
    h2 cd_hi = __builtin_elementwise_max(c, d), cd_lo = __builtin_elementwise_min(c, d);
    return __builtin_elementwise_max(__builtin_elementwise_min(ab_hi, cd_hi),
                                     __builtin_elementwise_max(ab_lo, cd_lo));
}

__device__ __forceinline__ void demo_acc(float v, int pyn, int pxn, int ady, int adx,
                                         float& accR, float& accG, float& accB) {
    bool isr = (pyn == 0) && (pxn == 1);
    bool isb = (pyn == 1) && (pxn == 0);
    float wrb = 0.25f * (float)((2 - ady) * (2 - adx));
    int man = ady + adx;
    float wg = (man == 0) ? 1.0f : ((man == 1) ? 0.25f : 0.0f);
    accR += isr ? wrb * v : 0.0f;
    accB += isb ? wrb * v : 0.0f;
    accG += (!isr && !isb) ? wg * v : 0.0f;
}

// ---------- vector LDS access helpers (CA = c0 & 3, 0 or 2) ----------
template <int CA>
__device__ __forceinline__ void load4u(const unsigned* row, int c0, unsigned w[4]) {
    if constexpr (CA == 0) {
        uint4 q = *reinterpret_cast<const uint4*>(row + c0);
        w[0] = q.x; w[1] = q.y; w[2] = q.z; w[3] = q.w;
    } else {
        uint2 a = *reinterpret_cast<const uint2*>(row + c0);
        uint2 b = *reinterpret_cast<const uint2*>(row + c0 + 2);
        w[0] = a.x; w[1] = a.y; w[2] = b.x; w[3] = b.y;
    }
}
// w[j] = row[c0-1+j], j<6
template <int CA>
__device__ __forceinline__ void load6u(const unsigned* row, int c0, unsigned w[6]) {
    if constexpr (CA == 0) {
        uint4 q = *reinterpret_cast<const uint4*>(row + c0);
        w[0] = row[c0 - 1];
        w[1] = q.x; w[2] = q.y; w[3] = q.z; w[4] = q.w;
        w[5] = row[c0 + 4];
    } else {
        uint4 a = *reinterpret_cast<const uint4*>(row + c0 - 2);
        uint4 b = *reinterpret_cast<const uint4*>(row + c0 + 2);
        w[0] = a.y; w[1] = a.z; w[2] = a.w; w[3] = b.x; w[4] = b.y; w[5] = b.z;
    }
}
template <int CA>
__device__ __forceinline__ void store4u(unsigned* row, int c0, const unsigned v[4]) {
    if constexpr (CA == 0) {
        *reinterpret_cast<uint4*>(row + c0) = make_uint4(v[0], v[1], v[2], v[3]);
    } else {
        *reinterpret_cast<uint2*>(row + c0) = make_uint2(v[0], v[1]);
        *reinterpret_cast<uint2*>(row + c0 + 2) = make_uint2(v[2], v[3]);
    }
}

// ---------- interior phase 1: u = -med8(diffs), 2 rows x 4 cols per thread ----------
// u rows [R0, R0+2*NRP), cols [C0, C0+4*NG). REQUIRES C0 % 4 == 2.
template <int R0, int NRP, int C0, int NG>
__device__ __forceinline__ void p1_int(const unsigned* __restrict__ sdRB,
                                       unsigned* __restrict__ uRB, int tid) {
    static_assert((C0 & 3) == 2, "p1_int needs C0 % 4 == 2");
    if (tid < NRP * NG) {
        int rp = tid / NG, g = tid - rp * NG;
        int r0 = R0 + 2 * rp;
        int c0 = C0 + 4 * g;
        int B = c0 - 2;                  // aligned
        unsigned w[4][6];                // cols c0-1 .. c0+4
#pragma unroll
        for (int i = 0; i < 4; ++i) {
            const unsigned* row = &sdRB[(r0 - 1 + i) * S + B];
            uint4 q0 = *reinterpret_cast<const uint4*>(row);
            uint4 q1 = *reinterpret_cast<const uint4*>(row + 4);
            w[i][0] = q0.y; w[i][1] = q0.z; w[i][2] = q0.w;
            w[i][3] = q1.x; w[i][4] = q1.y; w[i][5] = q1.z;
        }
#pragma unroll
        for (int rr = 0; rr < 2; ++rr) {
            unsigned rv[4];
#pragma unroll
            for (int i = 0; i < 4; ++i) {
                h2 m = med8p(u2h(w[rr][i]), u2h(w[rr][i + 1]), u2h(w[rr][i + 2]),
                             u2h(w[rr + 1][i]), u2h(w[rr + 1][i + 2]),
                             u2h(w[rr + 2][i]), u2h(w[rr + 2][i + 1]), u2h(w[rr + 2][i + 2]));
                rv[i] = h2u(-m);
            }
            store4u<2>(&uRB[(r0 + rr) * S], c0, rv);
        }
    }
}

// ---------- interior phase 2 (packed fp16): Rn,Bn,Gn on 2x4 px per thread ----------
template <int R0, int NRP, int C0, int NG, int CA, bool FINAL>
__device__ __forceinline__ void p2_int(_Float16* __restrict__ sG, unsigned* __restrict__ sdRB,
                                       const unsigned* __restrict__ uRB, int tid,
                                       int y0, int x0,
                                       float* __restrict__ oR, float* __restrict__ oG,
                                       float* __restrict__ oB) {
    if (tid < NRP * NG) {
        int rp = tid / NG, g = tid - rp * NG;
        int r0 = R0 + 2 * rp;
        int c0 = C0 + 4 * g;
        unsigned wm[4], wp[4], w0[6], w1[6];
        load4u<CA>(&uRB[(r0 - 1) * S], c0, wm);
        load6u<CA>(&uRB[(r0) * S], c0, w0);
        load6u<CA>(&uRB[(r0 + 1) * S], c0, w1);
        load4u<CA>(&uRB[(r0 + 2) * S], c0, wp);
        h2 ga0 = *reinterpret_cast<const h2*>(&sG[r0 * S + c0]);
        h2 ga1 = *reinterpret_cast<const h2*>(&sG[r0 * S + c0 + 2]);
        h2 gb0 = *reinterpret_cast<const h2*>(&sG[(r0 + 1) * S + c0]);
        h2 gb1 = *reinterpret_cast<const h2*>(&sG[(r0 + 1) * S + c0 + 2]);
        _Float16 gr0[4] = {ga0.x, ga0.y, ga1.x, ga1.y};
        _Float16 gr1[4] = {gb0.x, gb0.y, gb1.x, gb1.y};
        const h2 half2v = {(_Float16)0.5f, (_Float16)0.5f};

        unsigned nd0[4], nd1[4];
        float R4[2][4], G4[2][4], B4[2][4];
#pragma unroll
        for (int i = 0; i < 4; ++i) {
            {   // row r0
                h2 m = med4p(u2h(wm[i]), u2h(w0[i]), u2h(w0[i + 2]), u2h(w1[i + 1]));
                h2 uc = u2h(w0[i + 1]);
                h2 gg; gg.x = gr0[i]; gg.y = gr0[i];
                h2 RB = gg - uc;                       // (Rn, Bn)
                h2 Gn2 = ((m + swap16(m)) + (RB + swap16(RB))) * half2v;
                if constexpr (FINAL) {
                    R4[0][i] = (float)RB.x; B4[0][i] = (float)RB.y; G4[0][i] = (float)Gn2.x;
                } else {
                    nd0[i] = h2u(RB - Gn2);            // packed (Rn-Gn, Bn-Gn)
                    gr0[i] = Gn2.x;
                }
            }
            {   // row r0+1
                h2 m = med4p(u2h(w0[i + 1]), u2h(w1[i]), u2h(w1[i + 2]), u2h(wp[i]));
                h2 uc = u2h(w1[i + 1]);
                h2 gg; gg.x = gr1[i]; gg.y = gr1[i];
                h2 RB = gg - uc;
                h2 Gn2 = ((m + swap16(m)) + (RB + swap16(RB))) * half2v;
                if constexpr (FINAL) {
                    R4[1][i] = (float)RB.x; B4[1][i] = (float)RB.y; G4[1][i] = (float)Gn2.x;
                } else {
                    nd1[i] = h2u(RB - Gn2);
                    gr1[i] = Gn2.x;
                }
            }
        }
        if constexpr (FINAL) {
#pragma unroll
            for (int rr = 0; rr < 2; ++rr) {
                size_t o = (size_t)(y0 + r0 + rr) * WW + (x0 + c0);
                *reinterpret_cast<float4*>(&oR[o]) = make_float4(R4[rr][0], R4[rr][1], R4[rr][2], R4[rr][3]);
                *reinterpret_cast<float4*>(&oG[o]) = make_float4(G4[rr][0], G4[rr][1], G4[rr][2], G4[rr][3]);
                *reinterpret_cast<float4*>(&oB[o]) = make_float4(B4[rr][0], B4[rr][1], B4[rr][2], B4[rr][3]);
            }
        } else {
            h2 s00; s00.x = gr0[0]; s00.y = gr0[1];
            h2 s01; s01.x = gr0[2]; s01.y = gr0[3];
            h2 s10; s10.x = gr1[0]; s10.y = gr1[1];
            h2 s11; s11.x = gr1[2]; s11.y = gr1[3];
            *reinterpret_cast<h2*>(&sG[r0 * S + c0]) = s00;
            *reinterpret_cast<h2*>(&sG[r0 * S + c0 + 2]) = s01;
            *reinterpret_cast<h2*>(&sG[(r0 + 1) * S + c0]) = s10;
            *reinterpret_cast<h2*>(&sG[(r0 + 1) * S + c0 + 2]) = s11;
            store4u<CA>(&sdRB[r0 * S], c0, nd0);
            store4u<CA>(&sdRB[(r0 + 1) * S], c0, nd1);
        }
    }
}

// ---------- border (clamped, scalar) phase helpers ----------
__device__ void p1_b(const unsigned* sdRB, unsigned* uRB, int tid,
                     int y0, int x0, int rlo, int nr, int clo, int nc) {
    for (int t = tid; t < nr * nc; t += NTHR) {
        int r = rlo + t / nc, c = clo + t - (t / nc) * nc;
        int gy = clampi(y0 + r, 0, HH - 1), gx = clampi(x0 + c, 0, WW - 1);
        int rm = clampi(gy - 1, 0, HH - 1) - y0, rp = clampi(gy + 1, 0, HH - 1) - y0;
        int cm = clampi(gx - 1, 0, WW - 1) - x0, cp = clampi(gx + 1, 0, WW - 1) - x0;
        h2 m = med8p(u2h(sdRB[rm * S + cm]), u2h(sdRB[rm * S + c]), u2h(sdRB[rm * S + cp]),
                     u2h(sdRB[r * S + cm]), u2h(sdRB[r * S + cp]),
                     u2h(sdRB[rp * S + cm]), u2h(sdRB[rp * S + c]), u2h(sdRB[rp * S + cp]));
        uRB[r * S + c] = h2u(-m);
    }
}

__device__ void p2_b(_Float16* sG, unsigned* sdRB, const unsigned* uRB, int tid,
                     int y0, int x0, int rlo, int nr, int clo, int nc, bool fin,
                     float* oR, float* oG, float* oB) {
    for (int t = tid; t < nr * nc; t += NTHR) {
        int r = rlo + t / nc, c = clo + t - (t / nc) * nc;
        int gy = clampi(y0 + r, 0, HH - 1), gx = clampi(x0 + c, 0, WW - 1);
        int rm = clampi(gy - 1, 0, HH - 1) - y0, rp = clampi(gy + 1, 0, HH - 1) - y0;
        int cm = clampi(gx - 1, 0, WW - 1) - x0, cp = clampi(gx + 1, 0, WW - 1) - x0;
        h2 m = med4p(u2h(uRB[rm * S + c]), u2h(uRB[r * S + cm]),
                     u2h(uRB[r * S + cp]), u2h(uRB[rp * S + c]));
        h2 uc = u2h(uRB[r * S + c]);
        float Gc = (float)sG[r * S + c];
        float Rn = Gc - (float)uc.x, Bn = Gc - (float)uc.y;
        float Gn = 0.5f * ((float)m.x + (float)m.y + Rn + Bn);
        if (fin) {
            size_t o = (size_t)(y0 + r) * WW + (x0 + c);   // exact, in-range
            oR[o] = Rn; oG[o] = Gn; oB[o] = Bn;
        } else {
            sG[r * S + c] = (_Float16)Gn;
            sdRB[r * S + c] = packdiff(Rn - Gn, Bn - Gn);
        }
    }
}

// ---------- the fused kernel: 64x32 output tile, 512 threads ----------
// NOTE: no min-waves bound — residency is thread-capped at 4 blocks/CU anyway;
// freeing the register allocator lets the compiler keep phase working-sets in flight.
__global__ __launch_bounds__(512) void fused_kernel(const float* __restrict__ img,
                                                    float* __restrict__ dst) {
    // uRB: 3864 u32 | sdRB: 3864 u32 | sG: 3864 fp16 = 1932 u32 -> 38,640 B, 4 blocks/CU.
    __shared__ __align__(16) unsigned smem[9660];
    unsigned* uRB = smem;
    unsigned* sdRB = smem + RG * S;
    _Float16* sG = reinterpret_cast<_Float16*>(smem + 2 * RG * S);
    float* sI = reinterpret_cast<float*>(smem);   // border only: raw staged in uRB plane

    int bx = blockIdx.x, by = blockIdx.y, bb = blockIdx.z;
    int x0 = bx * 64 - 8, y0 = by * 32 - 7;       // region origin
    const float* im = img + (size_t)bb * PLANE;
    float* oR = dst + (size_t)bb * 3 * PLANE;
    float* oG = oR + PLANE;
    float* oB = oR + 2 * PLANE;
    int tid = threadIdx.x;
    bool interior = (bx >= 1 && bx <= 14 && by >= 1 && by <= 30);

    if (interior) {
        // ---- demosaick straight from global (coalesced float4 loads, no staging) ----
        if (tid < 22 * 19) {
            int qi = tid / 19, g = tid - (tid / 19) * 19;
            int rA = 1 + 2 * qi;          // anchor row; global gy even
            int B = 4 * g;                // w[i][j] = raw[y0+rA-1+i][x0+B+1+j]
            const float* base = im + (size_t)(y0 + rA - 1) * WW + (x0 + B);
            float w[4][6];
#pragma unroll
            for (int i = 0; i < 4; ++i) {
                float4 a = *reinterpret_cast<const float4*>(base + (size_t)i * WW);
                float4 b = *reinterpret_cast<const float4*>(base + (size_t)i * WW + 4);
                w[i][0] = a.y; w[i][1] = a.z; w[i][2] = a.w;
                w[i][3] = b.x; w[i][4] = b.y; w[i][5] = b.z;
            }
#pragma unroll
            for (int q = 0; q < 2; ++q) {
                int jb = 1 + 2 * q;
                float g00 = w[1][jb];
                float r00 = 0.5f * (w[1][jb - 1] + w[1][jb + 1]);
                float b00 = 0.5f * (w[0][jb] + w[2][jb]);
                float r01 = w[1][jb + 1];
                float g01 = 0.25f * (w[0][jb + 1] + w[2][jb + 1] + w[1][jb] + w[1][jb + 2]);
                float b01 = 0.25f * (w[0][jb] + w[0][jb + 2] + w[2][jb] + w[2][jb + 2]);
                float b10 = w[2][jb];
                float g10 = 0.25f * (w[1][jb] + w[3][jb] + w[2][jb - 1] + w[2][jb + 1]);
                float r10 = 0.25f * (w[1][jb - 1] + w[1][jb + 1] + w[3][jb - 1] + w[3][jb + 1]);
                float g11 = w[2][jb + 1];
                float r11 = 0.5f * (w[1][jb + 1] + w[3][jb + 1]);
                float b11 = 0.5f * (w[2][jb] + w[2][jb + 2]);
                int a0 = rA * S + 2 + 4 * g + 2 * q;
                h2 gh0; gh0.x = (_Float16)g00; gh0.y = (_Float16)g01;
                h2 gh1; gh1.x = (_Float16)g10; gh1.y = (_Float16)g11;
                *reinterpret_cast<h2*>(&sG[a0]) = gh0;
                *reinterpret_cast<h2*>(&sG[a0 + S]) = gh1;
                *reinterpret_cast<uint2*>(&sdRB[a0]) =
                    make_uint2(packdiff(r00 - g00, b00 - g00), packdiff(r01 - g01, b01 - g01));
                *reinterpret_cast<uint2*>(&sdRB[a0 + S]) =
                    make_uint2(packdiff(r10 - g10, b10 - g10), packdiff(r11 - g11, b11 - g11));
            }
        }
        __syncthreads();
        // ---- iteration 1: u rows 2..43, cols 2..77 (valid [3,76]) ----
        p1_int<2, 21, 2, 19>(sdRB, uRB, tid);
        __syncthreads();
        p2_int<3, 20, 4, 18, 0, false>(sG, sdRB, uRB, tid, y0, x0, oR, oG, oB);
        __syncthreads();
        // ---- iteration 2: u rows 4..41, cols 2..77 (valid [5,74]) ----
        p1_int<4, 19, 2, 19>(sdRB, uRB, tid);
        __syncthreads();
        p2_int<5, 18, 6, 17, 2, false>(sG, sdRB, uRB, tid, y0, x0, oR, oG, oB);
        __syncthreads();
        // ---- iteration 3: u rows 6..39, cols 6..73 (valid [7,72]) ----
        p1_int<6, 17, 6, 17>(sdRB, uRB, tid);
        __syncthreads();
        p2_int<7, 16, 8, 16, 0, true>(sG, sdRB, uRB, tid, y0, x0, oR, oG, oB);
    } else {
        // ---- border: stage raw (clamped) into the uRB plane, then scalar phases ----
        for (int t = tid; t < RG * S; t += NTHR) {
            int r = t / S, c = t - (t / S) * S;
            int gy = clampi(y0 + r, 0, HH - 1), gx = clampi(x0 + c, 0, WW - 1);
            sI[r * S + c] = im[(size_t)gy * WW + gx];
        }
        __syncthreads();
        {
            // demosaick on rows [1,45) x cols [2,78), values at clamped coords.
            for (int t = tid; t < 44 * 76; t += NTHR) {
                int r = 1 + t / 76, c = 2 + t - (t / 76) * 76;
                int gy = clampi(y0 + r, 0, HH - 1), gx = clampi(x0 + c, 0, WW - 1);
                float accR = 0.f, accG = 0.f, accB = 0.f;
#pragma unroll
                for (int dy = -1; dy <= 1; ++dy)
#pragma unroll
                    for (int dx = -1; dx <= 1; ++dx) {
                        int cy = clampi(gy + dy, 0, HH - 1);
                        int cx = clampi(gx + dx, 0, WW - 1);
                        float v = sI[(cy - y0) * S + (cx - x0)];
                        demo_acc(v, cy & 1, cx & 1, dy < 0 ? -dy : dy, dx < 0 ? -dx : dx,
                                 accR, accG, accB);
                    }
                sG[r * S + c] = (_Float16)accG;
                sdRB[r * S + c] = packdiff(accR - accG, accB - accG);
            }
        }
        __syncthreads();
        p1_b(sdRB, uRB, tid, y0, x0, 2, 42, 3, 74);
        __syncthreads();
        p2_b(sG, sdRB, uRB, tid, y0, x0, 3, 40, 4, 72, false, oR, oG, oB);
        __syncthreads();
        p1_b(sdRB, uRB, tid, y0, x0, 4, 38, 5, 70);
        __syncthreads();
        p2_b(sG, sdRB, uRB, tid, y0, x0, 5, 36, 6, 68, false, oR, oG, oB);
        __syncthreads();
        p1_b(sdRB, uRB, tid, y0, x0, 6, 34, 7, 66);
        __syncthreads();
        p2_b(sG, sdRB, uRB, tid, y0, x0, 7, 32, 8, 64, true, oR, oG, oB);
    }
}

extern "C" void kernel_launch(void* const* d_in, const int* in_sizes, int n_in,
                              void* d_out, int out_size, void* d_ws, size_t ws_size,
                              hipStream_t stream) {
    const float* img = (const float*)d_in[0];
    float* out = (float*)d_out;
    dim3 block(NTHR);
    dim3 grid(16, 32, NB);
    fused_kernel<<<grid, block, 0, stream>>>(img, out);
}

// Round 16
// 130.432 us; speedup vs baseline: 1.1939x; 1.0513x over previous
//
#include <hip/hip_runtime.h>

#define HH 1024
#define WW 1024
#define NB 8
constexpr int PLANE = HH * WW;

#define S   84   // LDS plane stride (u32 units), mult of 4
#define RG  78   // staged region rows (64 out + 14 halo)
#define NTHR 1024

typedef _Float16 h2 __attribute__((ext_vector_type(2)));

__device__ __forceinline__ int clampi(int v, int lo, int hi) {
    return v < lo ? lo : (v > hi ? hi : v);
}

union U2H { unsigned u; h2 h; };
__device__ __forceinline__ h2 u2h(unsigned v) { U2H x; x.u = v; return x.h; }
__device__ __forceinline__ unsigned h2u(h2 h) { U2H x; x.h = h; return x.u; }
__device__ __forceinline__ unsigned packdiff(float a, float b) {
    h2 h; h.x = (_Float16)a; h.y = (_Float16)b; return h2u(h);
}
__device__ __forceinline__ h2 swap16(h2 x) {
    unsigned u = h2u(x);
    return u2h(__builtin_amdgcn_alignbit(u, u, 16));
}

__device__ __forceinline__ void cswap2(h2& a, h2& b) {
    h2 lo = __builtin_elementwise_min(a, b);
    b = __builtin_elementwise_max(a, b);
    a = lo;
}

// rank 4 (0-indexed) of 8, both fp16 lanes. Pruned Batcher network (validated r1-r15).
__device__ __forceinline__ h2 med8p(h2 v0, h2 v1, h2 v2, h2 v3,
                                    h2 v4, h2 v5, h2 v6, h2 v7) {
    cswap2(v0, v1); cswap2(v2, v3); cswap2(v4, v5); cswap2(v6, v7);
    cswap2(v0, v2); cswap2(v1, v3); cswap2(v4, v6); cswap2(v5, v7);
    cswap2(v1, v2); cswap2(v5, v6);
    h2 p2 = __builtin_elementwise_min(v2, v6), p3 = __builtin_elementwise_min(v3, v7);
    h2 p4 = __builtin_elementwise_max(v0, v4), p5 = __builtin_elementwise_max(v1, v5);
    return __builtin_elementwise_max(__builtin_elementwise_min(p3, p5),
                                     __builtin_elementwise_max(p2, p4));
}

// rank 2 (0-indexed) of 4, both lanes.
__device__ __forceinline__ h2 med4p(h2 a, h2 b, h2 c, h2 d) {
    h2 ab_hi = __builtin_elementwise_max(a, b), ab_lo = __builtin_elementwise_min(a, b);
    h2 cd_hi = __builtin_elementwise_max(c, d), cd_lo = __builtin_elementwise_min(c, d);
    return __builtin_elementwise_max(__builtin_elementwise_min(ab_hi, cd_hi),
                                     __builtin_elementwise_max(ab_lo, cd_lo));
}

__device__ __forceinline__ void demo_acc(float v, int pyn, int pxn, int ady, int adx,
                                         float& accR, float& accG, float& accB) {
    bool isr = (pyn == 0) && (pxn == 1);
    bool isb = (pyn == 1) && (pxn == 0);
    float wrb = 0.25f * (float)((2 - ady) * (2 - adx));
    int man = ady + adx;
    float wg = (man == 0) ? 1.0f : ((man == 1) ? 0.25f : 0.0f);
    accR += isr ? wrb * v : 0.0f;
    accB += isb ? wrb * v : 0.0f;
    accG += (!isr && !isb) ? wg * v : 0.0f;
}

// ---------- vector LDS access helpers (CA = c0 & 3, 0 or 2) ----------
template <int CA>
__device__ __forceinline__ void load4u(const unsigned* row, int c0, unsigned w[4]) {
    if constexpr (CA == 0) {
        uint4 q = *reinterpret_cast<const uint4*>(row + c0);
        w[0] = q.x; w[1] = q.y; w[2] = q.z; w[3] = q.w;
    } else {
        uint2 a = *reinterpret_cast<const uint2*>(row + c0);
        uint2 b = *reinterpret_cast<const uint2*>(row + c0 + 2);
        w[0] = a.x; w[1] = a.y; w[2] = b.x; w[3] = b.y;
    }
}
// w[j] = row[c0-1+j], j<6
template <int CA>
__device__ __forceinline__ void load6u(const unsigned* row, int c0, unsigned w[6]) {
    if constexpr (CA == 0) {
        uint4 q = *reinterpret_cast<const uint4*>(row + c0);
        w[0] = row[c0 - 1];
        w[1] = q.x; w[2] = q.y; w[3] = q.z; w[4] = q.w;
        w[5] = row[c0 + 4];
    } else {
        uint4 a = *reinterpret_cast<const uint4*>(row + c0 - 2);
        uint4 b = *reinterpret_cast<const uint4*>(row + c0 + 2);
        w[0] = a.y; w[1] = a.z; w[2] = a.w; w[3] = b.x; w[4] = b.y; w[5] = b.z;
    }
}
template <int CA>
__device__ __forceinline__ void store4u(unsigned* row, int c0, const unsigned v[4]) {
    if constexpr (CA == 0) {
        *reinterpret_cast<uint4*>(row + c0) = make_uint4(v[0], v[1], v[2], v[3]);
    } else {
        *reinterpret_cast<uint2*>(row + c0) = make_uint2(v[0], v[1]);
        *reinterpret_cast<uint2*>(row + c0 + 2) = make_uint2(v[2], v[3]);
    }
}

// ---------- interior phase 1: u = -med8(diffs), 2 rows x 4 cols per thread ----------
template <int R0, int NRP, int C0, int NG>
__device__ __forceinline__ void p1_int(const unsigned* __restrict__ sdRB,
                                       unsigned* __restrict__ uRB, int tid) {
    static_assert((C0 & 3) == 2, "p1_int needs C0 % 4 == 2");
    if (tid < NRP * NG) {
        int rp = tid / NG, g = tid - rp * NG;
        int r0 = R0 + 2 * rp;
        int c0 = C0 + 4 * g;
        int B = c0 - 2;
        unsigned w[4][6];
#pragma unroll
        for (int i = 0; i < 4; ++i) {
            const unsigned* row = &sdRB[(r0 - 1 + i) * S + B];
            uint4 q0 = *reinterpret_cast<const uint4*>(row);
            uint4 q1 = *reinterpret_cast<const uint4*>(row + 4);
            w[i][0] = q0.y; w[i][1] = q0.z; w[i][2] = q0.w;
            w[i][3] = q1.x; w[i][4] = q1.y; w[i][5] = q1.z;
        }
#pragma unroll
        for (int rr = 0; rr < 2; ++rr) {
            unsigned rv[4];
#pragma unroll
            for (int i = 0; i < 4; ++i) {
                h2 m = med8p(u2h(w[rr][i]), u2h(w[rr][i + 1]), u2h(w[rr][i + 2]),
                             u2h(w[rr + 1][i]), u2h(w[rr + 1][i + 2]),
                             u2h(w[rr + 2][i]), u2h(w[rr + 2][i + 1]), u2h(w[rr + 2][i + 2]));
                rv[i] = h2u(-m);
            }
            store4u<2>(&uRB[(r0 + rr) * S], c0, rv);
        }
    }
}

// ---------- interior phase 2 (packed fp16): Rn,Bn,Gn on 2x4 px per thread ----------
template <int R0, int NRP, int C0, int NG, int CA, bool FINAL>
__device__ __forceinline__ void p2_int(_Float16* __restrict__ sG, unsigned* __restrict__ sdRB,
                                       const unsigned* __restrict__ uRB, int tid,
                                       int y0, int x0,
                                       float* __restrict__ oR, float* __restrict__ oG,
                                       float* __restrict__ oB) {
    if (tid < NRP * NG) {
        int rp = tid / NG, g = tid - rp * NG;
        int r0 = R0 + 2 * rp;
        int c0 = C0 + 4 * g;
        unsigned wm[4], wp[4], w0[6], w1[6];
        load4u<CA>(&uRB[(r0 - 1) * S], c0, wm);
        load6u<CA>(&uRB[(r0) * S], c0, w0);
        load6u<CA>(&uRB[(r0 + 1) * S], c0, w1);
        load4u<CA>(&uRB[(r0 + 2) * S], c0, wp);
        h2 ga0 = *reinterpret_cast<const h2*>(&sG[r0 * S + c0]);
        h2 ga1 = *reinterpret_cast<const h2*>(&sG[r0 * S + c0 + 2]);
        h2 gb0 = *reinterpret_cast<const h2*>(&sG[(r0 + 1) * S + c0]);
        h2 gb1 = *reinterpret_cast<const h2*>(&sG[(r0 + 1) * S + c0 + 2]);
        _Float16 gr0[4] = {ga0.x, ga0.y, ga1.x, ga1.y};
        _Float16 gr1[4] = {gb0.x, gb0.y, gb1.x, gb1.y};
        const h2 half2v = {(_Float16)0.5f, (_Float16)0.5f};

        unsigned nd0[4], nd1[4];
        float R4[2][4], G4[2][4], B4[2][4];
#pragma unroll
        for (int i = 0; i < 4; ++i) {
            {   // row r0
                h2 m = med4p(u2h(wm[i]), u2h(w0[i]), u2h(w0[i + 2]), u2h(w1[i + 1]));
                h2 uc = u2h(w0[i + 1]);
                h2 gg; gg.x = gr0[i]; gg.y = gr0[i];
                h2 RB = gg - uc;
                h2 Gn2 = ((m + swap16(m)) + (RB + swap16(RB))) * half2v;
                if constexpr (FINAL) {
                    R4[0][i] = (float)RB.x; B4[0][i] = (float)RB.y; G4[0][i] = (float)Gn2.x;
                } else {
                    nd0[i] = h2u(RB - Gn2);
                    gr0[i] = Gn2.x;
                }
            }
            {   // row r0+1
                h2 m = med4p(u2h(w0[i + 1]), u2h(w1[i]), u2h(w1[i + 2]), u2h(wp[i]));
                h2 uc = u2h(w1[i + 1]);
                h2 gg; gg.x = gr1[i]; gg.y = gr1[i];
                h2 RB = gg - uc;
                h2 Gn2 = ((m + swap16(m)) + (RB + swap16(RB))) * half2v;
                if constexpr (FINAL) {
                    R4[1][i] = (float)RB.x; B4[1][i] = (float)RB.y; G4[1][i] = (float)Gn2.x;
                } else {
                    nd1[i] = h2u(RB - Gn2);
                    gr1[i] = Gn2.x;
                }
            }
        }
        if constexpr (FINAL) {
#pragma unroll
            for (int rr = 0; rr < 2; ++rr) {
                size_t o = (size_t)(y0 + r0 + rr) * WW + (x0 + c0);
                *reinterpret_cast<float4*>(&oR[o]) = make_float4(R4[rr][0], R4[rr][1], R4[rr][2], R4[rr][3]);
                *reinterpret_cast<float4*>(&oG[o]) = make_float4(G4[rr][0], G4[rr][1], G4[rr][2], G4[rr][3]);
                *reinterpret_cast<float4*>(&oB[o]) = make_float4(B4[rr][0], B4[rr][1], B4[rr][2], B4[rr][3]);
            }
        } else {
            h2 s00; s00.x = gr0[0]; s00.y = gr0[1];
            h2 s01; s01.x = gr0[2]; s01.y = gr0[3];
            h2 s10; s10.x = gr1[0]; s10.y = gr1[1];
            h2 s11; s11.x = gr1[2]; s11.y = gr1[3];
            *reinterpret_cast<h2*>(&sG[r0 * S + c0]) = s00;
            *reinterpret_cast<h2*>(&sG[r0 * S + c0 + 2]) = s01;
            *reinterpret_cast<h2*>(&sG[(r0 + 1) * S + c0]) = s10;
            *reinterpret_cast<h2*>(&sG[(r0 + 1) * S + c0 + 2]) = s11;
            store4u<CA>(&sdRB[r0 * S], c0, nd0);
            store4u<CA>(&sdRB[(r0 + 1) * S], c0, nd1);
        }
    }
}

// ---------- border (clamped, scalar) phase helpers ----------
__device__ void p1_b(const unsigned* sdRB, unsigned* uRB, int tid,
                     int y0, int x0, int rlo, int nr, int clo, int nc) {
    for (int t = tid; t < nr * nc; t += NTHR) {
        int r = rlo + t / nc, c = clo + t - (t / nc) * nc;
        int gy = clampi(y0 + r, 0, HH - 1), gx = clampi(x0 + c, 0, WW - 1);
        int rm = clampi(gy - 1, 0, HH - 1) - y0, rp = clampi(gy + 1, 0, HH - 1) - y0;
        int cm = clampi(gx - 1, 0, WW - 1) - x0, cp = clampi(gx + 1, 0, WW - 1) - x0;
        h2 m = med8p(u2h(sdRB[rm * S + cm]), u2h(sdRB[rm * S + c]), u2h(sdRB[rm * S + cp]),
                     u2h(sdRB[r * S + cm]), u2h(sdRB[r * S + cp]),
                     u2h(sdRB[rp * S + cm]), u2h(sdRB[rp * S + c]), u2h(sdRB[rp * S + cp]));
        uRB[r * S + c] = h2u(-m);
    }
}

__device__ void p2_b(_Float16* sG, unsigned* sdRB, const unsigned* uRB, int tid,
                     int y0, int x0, int rlo, int nr, int clo, int nc, bool fin,
                     float* oR, float* oG, float* oB) {
    for (int t = tid; t < nr * nc; t += NTHR) {
        int r = rlo + t / nc, c = clo + t - (t / nc) * nc;
        int gy = clampi(y0 + r, 0, HH - 1), gx = clampi(x0 + c, 0, WW - 1);
        int rm = clampi(gy - 1, 0, HH - 1) - y0, rp = clampi(gy + 1, 0, HH - 1) - y0;
        int cm = clampi(gx - 1, 0, WW - 1) - x0, cp = clampi(gx + 1, 0, WW - 1) - x0;
        h2 m = med4p(u2h(uRB[rm * S + c]), u2h(uRB[r * S + cm]),
                     u2h(uRB[r * S + cp]), u2h(uRB[rp * S + c]));
        h2 uc = u2h(uRB[r * S + c]);
        float Gc = (float)sG[r * S + c];
        float Rn = Gc - (float)uc.x, Bn = Gc - (float)uc.y;
        float Gn = 0.5f * ((float)m.x + (float)m.y + Rn + Bn);
        if (fin) {
            size_t o = (size_t)(y0 + r) * WW + (x0 + c);   // exact, in-range
            oR[o] = Rn; oG[o] = Gn; oB[o] = Bn;
        } else {
            sG[r * S + c] = (_Float16)Gn;
            sdRB[r * S + c] = packdiff(Rn - Gn, Bn - Gn);
        }
    }
}

// ---------- the fused kernel: 64x64 output tile, 1024 threads ----------
__global__ __launch_bounds__(1024) void fused_kernel(const float* __restrict__ img,
                                                     float* __restrict__ dst) {
    // uRB: 6552 u32 | sdRB: 6552 u32 | sG: 6552 fp16 = 3276 u32
    // total 16380 u32 = 65,520 B -> 2 blocks/CU = 2048 threads/CU (HW cap).
    __shared__ __align__(16) unsigned smem[16380];
    unsigned* uRB = smem;
    unsigned* sdRB = smem + RG * S;
    _Float16* sG = reinterpret_cast<_Float16*>(smem + 2 * RG * S);
    float* sI = reinterpret_cast<float*>(smem);   // border only: raw staged in uRB plane

    int bx = blockIdx.x, by = blockIdx.y, bb = blockIdx.z;
    int x0 = bx * 64 - 8, y0 = by * 64 - 7;       // region origin
    const float* im = img + (size_t)bb * PLANE;
    float* oR = dst + (size_t)bb * 3 * PLANE;
    float* oG = oR + PLANE;
    float* oB = oR + 2 * PLANE;
    int tid = threadIdx.x;
    bool interior = (bx >= 1 && bx <= 14 && by >= 1 && by <= 14);

    if (interior) {
        // ---- demosaick straight from global: 38 quad-rows x 19 quad-pair-cols ----
        if (tid < 38 * 19) {
            int qi = tid / 19, g = tid - (tid / 19) * 19;
            int rA = 1 + 2 * qi;          // anchor row; global gy even
            int B = 4 * g;
            const float* base = im + (size_t)(y0 + rA - 1) * WW + (x0 + B);
            float w[4][6];
#pragma unroll
            for (int i = 0; i < 4; ++i) {
                float4 a = *reinterpret_cast<const float4*>(base + (size_t)i * WW);
                float4 b = *reinterpret_cast<const float4*>(base + (size_t)i * WW + 4);
                w[i][0] = a.y; w[i][1] = a.z; w[i][2] = a.w;
                w[i][3] = b.x; w[i][4] = b.y; w[i][5] = b.z;
            }
#pragma unroll
            for (int q = 0; q < 2; ++q) {
                int jb = 1 + 2 * q;
                float g00 = w[1][jb];
                float r00 = 0.5f * (w[1][jb - 1] + w[1][jb + 1]);
                float b00 = 0.5f * (w[0][jb] + w[2][jb]);
                float r01 = w[1][jb + 1];
                float g01 = 0.25f * (w[0][jb + 1] + w[2][jb + 1] + w[1][jb] + w[1][jb + 2]);
                float b01 = 0.25f * (w[0][jb] + w[0][jb + 2] + w[2][jb] + w[2][jb + 2]);
                float b10 = w[2][jb];
                float g10 = 0.25f * (w[1][jb] + w[3][jb] + w[2][jb - 1] + w[2][jb + 1]);
                float r10 = 0.25f * (w[1][jb - 1] + w[1][jb + 1] + w[3][jb - 1] + w[3][jb + 1]);
                float g11 = w[2][jb + 1];
                float r11 = 0.5f * (w[1][jb + 1] + w[3][jb + 1]);
                float b11 = 0.5f * (w[2][jb] + w[2][jb + 2]);
                int a0 = rA * S + 2 + 4 * g + 2 * q;
                h2 gh0; gh0.x = (_Float16)g00; gh0.y = (_Float16)g01;
                h2 gh1; gh1.x = (_Float16)g10; gh1.y = (_Float16)g11;
                *reinterpret_cast<h2*>(&sG[a0]) = gh0;
                *reinterpret_cast<h2*>(&sG[a0 + S]) = gh1;
                *reinterpret_cast<uint2*>(&sdRB[a0]) =
                    make_uint2(packdiff(r00 - g00, b00 - g00), packdiff(r01 - g01, b01 - g01));
                *reinterpret_cast<uint2*>(&sdRB[a0 + S]) =
                    make_uint2(packdiff(r10 - g10, b10 - g10), packdiff(r11 - g11, b11 - g11));
            }
        }
        __syncthreads();
        // ---- iteration 1: u rows 2..75, cols 2..77 (valid [3,76]) ----
        p1_int<2, 37, 2, 19>(sdRB, uRB, tid);
        __syncthreads();
        p2_int<3, 36, 4, 18, 0, false>(sG, sdRB, uRB, tid, y0, x0, oR, oG, oB);
        __syncthreads();
        // ---- iteration 2: u rows 4..73, cols 2..77 (valid [5,74]) ----
        p1_int<4, 35, 2, 19>(sdRB, uRB, tid);
        __syncthreads();
        p2_int<5, 34, 6, 17, 2, false>(sG, sdRB, uRB, tid, y0, x0, oR, oG, oB);
        __syncthreads();
        // ---- iteration 3: u rows 6..71, cols 6..73 (valid [7,72]) ----
        p1_int<6, 33, 6, 17>(sdRB, uRB, tid);
        __syncthreads();
        p2_int<7, 32, 8, 16, 0, true>(sG, sdRB, uRB, tid, y0, x0, oR, oG, oB);
    } else {
        // ---- border: stage raw (clamped) into the uRB plane, then scalar phases ----
        for (int t = tid; t < RG * S; t += NTHR) {
            int r = t / S, c = t - (t / S) * S;
            int gy = clampi(y0 + r, 0, HH - 1), gx = clampi(x0 + c, 0, WW - 1);
            sI[r * S + c] = im[(size_t)gy * WW + gx];
        }
        __syncthreads();
        {
            // demosaick on rows [1,77) x cols [2,78), values at clamped coords.
            for (int t = tid; t < 76 * 76; t += NTHR) {
                int r = 1 + t / 76, c = 2 + t - (t / 76) * 76;
                int gy = clampi(y0 + r, 0, HH - 1), gx = clampi(x0 + c, 0, WW - 1);
                float accR = 0.f, accG = 0.f, accB = 0.f;
#pragma unroll
                for (int dy = -1; dy <= 1; ++dy)
#pragma unroll
                    for (int dx = -1; dx <= 1; ++dx) {
                        int cy = clampi(gy + dy, 0, HH - 1);
                        int cx = clampi(gx + dx, 0, WW - 1);
                        float v = sI[(cy - y0) * S + (cx - x0)];
                        demo_acc(v, cy & 1, cx & 1, dy < 0 ? -dy : dy, dx < 0 ? -dx : dx,
                                 accR, accG, accB);
                    }
                sG[r * S + c] = (_Float16)accG;
                sdRB[r * S + c] = packdiff(accR - accG, accB - accG);
            }
        }
        __syncthreads();
        p1_b(sdRB, uRB, tid, y0, x0, 2, 74, 3, 74);
        __syncthreads();
        p2_b(sG, sdRB, uRB, tid, y0, x0, 3, 72, 4, 72, false, oR, oG, oB);
        __syncthreads();
        p1_b(sdRB, uRB, tid, y0, x0, 4, 70, 5, 70);
        __syncthreads();
        p2_b(sG, sdRB, uRB, tid, y0, x0, 5, 68, 6, 68, false, oR, oG, oB);
        __syncthreads();
        p1_b(sdRB, uRB, tid, y0, x0, 6, 66, 7, 66);
        __syncthreads();
        p2_b(sG, sdRB, uRB, tid, y0, x0, 7, 64, 8, 64, true, oR, oG, oB);
    }
}

extern "C" void kernel_launch(void* const* d_in, const int* in_sizes, int n_in,
                              void* d_out, int out_size, void* d_ws, size_t ws_size,
                              hipStream_t stream) {
    const float* img = (const float*)d_in[0];
    float* out = (float*)d_out;
    dim3 block(NTHR);
    dim3 grid(16, 16, NB);
    fused_kernel<<<grid, block, 0, stream>>>(img, out);
}